// Round 3
// baseline (412.510 us; speedup 1.0000x reference)
//
#include <hip/hip_runtime.h>

// HybridQLSTMQuantum, fused single kernel, MI355X — MFMA phase-A version.
//
// qgate identity (verified analytically):
//   qgate(angles)[w] = prod_{j<=w} cos(angles[j])
//
// Structure: one block per batch row b (grid=256, block=256 = 4 waves).
//   Phase A (bf16 path): per-block 256x32x256 GEMM via mfma_f32_16x16x32_bf16.
//     Wave v computes t in [v*64, v*64+64): 4 m-tiles x 2 n-tiles x 8 k-steps.
//     A-frag: lane l reads X[t0+(l&15)][(l>>4)*8 + ks*32 ...] — contiguous 16B.
//     B-frag: lane l reads W_{o=n0+(l&15)}[(l>>4)*8 + ks*32 ...] — contiguous 16B.
//     C/D: row=(l>>4)*4+reg, col=l&15  ->  As[t][o].  One barrier total.
//   Phase B: 256-step serial recurrence on lanes 0..31 of wave 0 (as before):
//     h-broadcast via v_readlane, cos-cumprod via DPP row_shr, gate gather
//     via ds_swizzle, unified sigmoid/tanh 1 - q/(exp(q*E)+1).
// Runtime dtype sniff retained; f32 storage falls back to VALU dots.
// All parameter loads sanitized: NaN output impossible by construction.

#define S_LEN 256
#define BATCH 256
#define DIMK  256
#define FAN   264

typedef __attribute__((ext_vector_type(8))) short short8;
typedef __attribute__((ext_vector_type(4))) float f32x4;

__device__ __forceinline__ float b2f(unsigned short u) {
    union { unsigned u; float f; } v; v.u = ((unsigned)u) << 16; return v.f;
}
__device__ __forceinline__ unsigned short f2b(float f) {
    union { float f; unsigned u; } v; v.f = f;
    unsigned r = v.u + 0x7fffu + ((v.u >> 16) & 1u);  // RNE
    return (unsigned short)(r >> 16);
}
__device__ __forceinline__ float sane(float x) {
    return (__builtin_fabsf(x) < 1e30f) ? x : 0.f;   // NaN compares false -> 0
}
__device__ __forceinline__ float ldE(const void* p, int idx, bool f32) {
    return f32 ? ((const float*)p)[idx] : b2f(((const unsigned short*)p)[idx]);
}
__device__ __forceinline__ void stE(void* p, long idx, float v, bool f32) {
    if (f32) ((float*)p)[idx] = v;
    else     ((unsigned short*)p)[idx] = f2b(v);
}

// DPP row_shr:K within 16-lane rows (CTRL = 0x110|K); invalid lanes keep old.
template<int CTRL>
__device__ __forceinline__ float dpp_f(float x) {
    int xi = __builtin_bit_cast(int, x);
    int r = __builtin_amdgcn_update_dpp(xi, xi, CTRL, 0xF, 0xF, false);
    return __builtin_bit_cast(float, r);
}
// ds_swizzle BitMode: src_lane = ((lane & and) | or) ^ xor, imm = xor<<10|or<<5|and
template<int IMM>
__device__ __forceinline__ float swz_f(float x) {
    return __builtin_bit_cast(float,
        __builtin_amdgcn_ds_swizzle(__builtin_bit_cast(int, x), IMM));
}
__device__ __forceinline__ float rdlane_f(float x, int l) {
    return __builtin_bit_cast(float,
        __builtin_amdgcn_readlane(__builtin_bit_cast(int, x), l));
}

__device__ __forceinline__ float dot256_f32(const float* __restrict__ x,
                                            const float* __restrict__ w) {
    const float4* __restrict__ xv = (const float4*)x;
    const float4* __restrict__ wv = (const float4*)w;
    float a0 = 0.f, a1 = 0.f, a2 = 0.f, a3 = 0.f;
#pragma unroll 8
    for (int k = 0; k < 64; ++k) {
        float4 xu = xv[k], wu = wv[k];
        a0 = fmaf(xu.x, wu.x, a0);
        a1 = fmaf(xu.y, wu.y, a1);
        a2 = fmaf(xu.z, wu.z, a2);
        a3 = fmaf(xu.w, wu.w, a3);
    }
    return (a0 + a1) + (a2 + a3);
}

__global__ __launch_bounds__(256) void qlstm_fused(
    const void* __restrict__ X,  const void* __restrict__ hx, const void* __restrict__ cx,
    const void* __restrict__ Wf, const void* __restrict__ bf_,
    const void* __restrict__ Wi, const void* __restrict__ bi_,
    const void* __restrict__ Wu, const void* __restrict__ bu_,
    const void* __restrict__ Wo, const void* __restrict__ bo_,
    const void* __restrict__ tf, const void* __restrict__ ti,
    const void* __restrict__ tu, const void* __restrict__ to_,
    void* __restrict__ out)
{
    __shared__ float As[S_LEN][32];   // 32 KiB: A[t][o]
    __shared__ int s_isf32;

    const int tid = threadIdx.x;
    const int b   = blockIdx.x;

    // ---- dtype sniff: bf16 storage -> even-index ushorts are bf16 of N(0,1)
    // (exponent near 127); fp32 -> low mantissa bits, exponent-field uniform.
    if (tid == 0) {
        const unsigned short* u = (const unsigned short*)X;
        int hits = 0;
        for (int i = 0; i < 64; ++i) {
            int e = (u[2 * i] >> 7) & 0xFF;
            if (e >= 110 && e <= 135) ++hits;
        }
        s_isf32 = (hits < 32) ? 1 : 0;
    }
    __syncthreads();
    const bool f32 = (s_isf32 != 0);

    if (!f32) {
        // ---- phase A via MFMA: wave v owns t in [v*64, v*64+64)
        const int wv = tid >> 6;
        const int l  = tid & 63;
        const int lr = l & 15;          // row-in-tile / col-in-tile
        const int lh = l >> 4;          // k-subgroup (0..3)
        const unsigned short* Wp[4] = {
            (const unsigned short*)Wf, (const unsigned short*)Wi,
            (const unsigned short*)Wu, (const unsigned short*)Wo };

        // B-fragments: bfrag[n][ks] covers k = ks*32 + lh*8 .. +7, col n*16+lr
        short8 bfrag[2][8];
#pragma unroll
        for (int n = 0; n < 2; ++n) {
            const int o = n * 16 + lr, g = o >> 3, w = o & 7;
            const unsigned short* wr = Wp[g] + w * FAN + lh * 8;
#pragma unroll
            for (int ks = 0; ks < 8; ++ks)
                bfrag[n][ks] = *(const short8*)(wr + ks * 32);
        }

        const int t0 = wv * 64;
#pragma unroll
        for (int mt = 0; mt < 4; ++mt) {
            const int tr = t0 + mt * 16 + lr;
            const unsigned short* xr =
                (const unsigned short*)X + ((long)tr * BATCH + b) * DIMK + lh * 8;
            short8 afrag[8];
#pragma unroll
            for (int ks = 0; ks < 8; ++ks)
                afrag[ks] = *(const short8*)(xr + ks * 32);
            f32x4 acc0 = {0.f, 0.f, 0.f, 0.f};
            f32x4 acc1 = {0.f, 0.f, 0.f, 0.f};
#pragma unroll
            for (int ks = 0; ks < 8; ++ks) {
                acc0 = __builtin_amdgcn_mfma_f32_16x16x32_bf16(
                           afrag[ks], bfrag[0][ks], acc0, 0, 0, 0);
                acc1 = __builtin_amdgcn_mfma_f32_16x16x32_bf16(
                           afrag[ks], bfrag[1][ks], acc1, 0, 0, 0);
            }
            const int trow = t0 + mt * 16 + lh * 4;  // C row = (l>>4)*4 + reg
#pragma unroll
            for (int r = 0; r < 4; ++r) {
                As[trow + r][lr]      = sane(acc0[r]);
                As[trow + r][16 + lr] = sane(acc1[r]);
            }
        }
    } else {
        // ---- f32 fallback: plain VALU dots, all 256 threads
        const int o = tid & 31, g = o >> 3, w = o & 7;
        const float* Wp4[4] = { (const float*)Wf, (const float*)Wi,
                                (const float*)Wu, (const float*)Wo };
        const float* wr = Wp4[g] + w * FAN;
        for (int tl = tid >> 5; tl < S_LEN; tl += 8) {
            float acc = dot256_f32((const float*)X + ((long)tl * BATCH + b) * DIMK, wr);
            As[tl][o] = sane(acc);
        }
    }

    // ---- recurrence state (lanes 0..31 of wave 0)
    float Wh[8];
    float bt = 0.f, h = 0.f, c = 0.f, qv = 1.f;
    int rw = 0, rg = 0;
    if (tid < 32) {
        rw = tid & 7; rg = tid >> 3;
        const void* W  = (rg == 0) ? Wf  : (rg == 1) ? Wi  : (rg == 2) ? Wu  : Wo;
        const void* bg = (rg == 0) ? bf_ : (rg == 1) ? bi_ : (rg == 2) ? bu_ : bo_;
        const void* tg = (rg == 0) ? tf  : (rg == 1) ? ti  : (rg == 2) ? tu  : to_;
        const int wr = rw * FAN;
#pragma unroll
        for (int j = 0; j < 8; ++j)
            Wh[j] = sane(ldE(W, wr + DIMK + j, f32));
        bt = sane(ldE(bg, rw, f32)) + sane(ldE(tg, rw, f32));
        h  = sane(ldE(hx, b * 8 + rw, f32));
        c  = sane(ldE(cx, b * 8 + rw, f32));
        qv = (rg == 2) ? 2.f : 1.f;   // 1 -> sigmoid, 2 -> tanh (unified form)
    }
    __syncthreads();   // As complete; uniform barrier

    // ---- phase B: 256-step serial recurrence
    if (tid < 32) {
        float a_cur = As[0][tid];
        for (int t = 0; t < S_LEN; ++t) {
            const int tn = (t < S_LEN - 1) ? (t + 1) : t;
            float a_nxt = As[tn][tid];          // prefetch next step's input

            // h-dot via v_readlane (h replicated across gate groups)
            float d0 = 0.f, d1 = 0.f;
#pragma unroll
            for (int j = 0; j < 8; j += 2) {
                d0 = fmaf(rdlane_f(h, j),     Wh[j],     d0);
                d1 = fmaf(rdlane_f(h, j + 1), Wh[j + 1], d1);
            }
            float ang = a_cur + bt + (d0 + d1);
            float e = __cosf(ang);

            // inclusive cumprod over 8-lane group via DPP row_shr
            { float v = dpp_f<0x111>(e); e = (rw >= 1) ? e * v : e; }
            { float v = dpp_f<0x112>(e); e = (rw >= 2) ? e * v : e; }
            { float v = dpp_f<0x114>(e); e = (rw >= 4) ? e * v : e; }

            // own-gate nonlinearity: 1 - q/(exp(q*E)+1); q=1 sigm, q=2 tanh
            float ez  = __expf(qv * e);
            float val = 1.f - __fdividef(qv, ez + 1.f);

            // gather the 4 transformed gates for this wire (one LDS round)
            float fg = swz_f<0x007>(val);          // lane  w
            float ig = swz_f<0x107>(val);          // lane  8+w
            float ug = swz_f<0x207>(val);          // lane 16+w
            float og = swz_f<0x307>(val);          // lane 24+w

            c = fmaf(fg, c, ig * ug);
            float e2 = __expf(2.f * c);
            float th = 1.f - __fdividef(2.f, e2 + 1.f);
            h = og * th;

            if (rg == 0)
                stE(out, (long)t * 2048 + b * 8 + rw, h, f32);
            a_cur = a_nxt;
        }
        if (rg == 0) {
            stE(out, 524288L + b * 8 + rw, h, f32);   // hT
            stE(out, 526336L + b * 8 + rw, c, f32);   // cT
        }
    }
}

extern "C" void kernel_launch(void* const* d_in, const int* in_sizes, int n_in,
                              void* d_out, int out_size, void* d_ws, size_t ws_size,
                              hipStream_t stream) {
    qlstm_fused<<<dim3(BATCH), dim3(256), 0, stream>>>(
        d_in[0], d_in[1], d_in[2],
        d_in[3], d_in[4], d_in[5], d_in[6],
        d_in[7], d_in[8], d_in[9], d_in[10],
        d_in[11], d_in[12], d_in[13], d_in[14],
        d_out);
}

// Round 4
// 285.681 us; speedup vs baseline: 1.4440x; 1.4440x over previous
//
#include <hip/hip_runtime.h>

// HybridQLSTMQuantum, fused single kernel, MI355X — wide-block pipelined v4.
//
// qgate identity (verified analytically):
//   qgate(angles)[w] = prod_{j<=w} cos(angles[j])
//
// R3 post-mortem: MfmaUtil==0.0 proved the dtype sniff selects the fp32
// branch — inputs are fp32. Phase A is therefore a latency-bound f32 GEMM;
// at 4 waves/block (1 wave/SIMD) there is no TLP to hide load latency.
//
// v4 structure: one block per batch row b, grid=256, block=1024 (16 waves,
// 4 waves/SIMD -> load latency hidden by TLP).
//   Prologue: all 1024 threads fill chunk 0 (1 dot each).
//   Pipeline over 8 chunks of 32 timesteps:
//     waves 1-15 (960 thr): fill chunk ch+1 (1024 dots; q<64 do two)
//     wave 0 lanes 0-31   : 32-step recurrence for chunk ch
//       h-broadcast via v_readlane, cos-cumprod via DPP row_shr,
//       gate gather via ds_swizzle, unified sigm/tanh 1-q/(exp(qE)+1).
//   One uniform __syncthreads per chunk (outside all tid guards).
// Runtime dtype sniff retained (bf16 path kept as VALU dots).
// All parameter loads sanitized: NaN output impossible by construction.

#define S_LEN 256
#define BATCH 256
#define DIMK  256
#define FAN   264
#define CHUNK 32
#define NCH   8      // S_LEN / CHUNK

__device__ __forceinline__ float lo16f(unsigned u) {
    union { unsigned u; float f; } v; v.u = u << 16; return v.f;
}
__device__ __forceinline__ float hi16f(unsigned u) {
    union { unsigned u; float f; } v; v.u = u & 0xffff0000u; return v.f;
}
__device__ __forceinline__ float b2f(unsigned short u) {
    union { unsigned u; float f; } v; v.u = ((unsigned)u) << 16; return v.f;
}
__device__ __forceinline__ unsigned short f2b(float f) {
    union { float f; unsigned u; } v; v.f = f;
    unsigned r = v.u + 0x7fffu + ((v.u >> 16) & 1u);  // RNE
    return (unsigned short)(r >> 16);
}
__device__ __forceinline__ float sane(float x) {
    return (__builtin_fabsf(x) < 1e30f) ? x : 0.f;   // NaN compares false -> 0
}
__device__ __forceinline__ float ldE(const void* p, int idx, bool f32) {
    return f32 ? ((const float*)p)[idx] : b2f(((const unsigned short*)p)[idx]);
}
__device__ __forceinline__ void stE(void* p, long idx, float v, bool f32) {
    if (f32) ((float*)p)[idx] = v;
    else     ((unsigned short*)p)[idx] = f2b(v);
}

// DPP row_shr:K within 16-lane rows (CTRL = 0x110|K); invalid lanes keep old.
template<int CTRL>
__device__ __forceinline__ float dpp_f(float x) {
    int xi = __builtin_bit_cast(int, x);
    int r = __builtin_amdgcn_update_dpp(xi, xi, CTRL, 0xF, 0xF, false);
    return __builtin_bit_cast(float, r);
}
// ds_swizzle BitMode: src_lane = ((lane & and) | or) ^ xor, imm = xor<<10|or<<5|and
template<int IMM>
__device__ __forceinline__ float swz_f(float x) {
    return __builtin_bit_cast(float,
        __builtin_amdgcn_ds_swizzle(__builtin_bit_cast(int, x), IMM));
}
__device__ __forceinline__ float rdlane_f(float x, int l) {
    return __builtin_bit_cast(float,
        __builtin_amdgcn_readlane(__builtin_bit_cast(int, x), l));
}

// 256-long dots with explicit 16B vector loads (bases 16B-aligned:
// x row = (t*256+b)*256 elems; W row stride = 264 elems -> 528B/1056B).
__device__ __forceinline__ float dot256_bf16(const unsigned short* __restrict__ x,
                                             const unsigned short* __restrict__ w) {
    const uint4* __restrict__ xv = (const uint4*)x;
    const uint4* __restrict__ wv = (const uint4*)w;
    float a0 = 0.f, a1 = 0.f, a2 = 0.f, a3 = 0.f;
#pragma unroll 8
    for (int k = 0; k < 32; ++k) {
        uint4 xu = xv[k], wu = wv[k];
        a0 = fmaf(lo16f(xu.x), lo16f(wu.x), a0);
        a1 = fmaf(hi16f(xu.x), hi16f(wu.x), a1);
        a2 = fmaf(lo16f(xu.y), lo16f(wu.y), a2);
        a3 = fmaf(hi16f(xu.y), hi16f(wu.y), a3);
        a0 = fmaf(lo16f(xu.z), lo16f(wu.z), a0);
        a1 = fmaf(hi16f(xu.z), hi16f(wu.z), a1);
        a2 = fmaf(lo16f(xu.w), lo16f(wu.w), a2);
        a3 = fmaf(hi16f(xu.w), hi16f(wu.w), a3);
    }
    return (a0 + a1) + (a2 + a3);
}
__device__ __forceinline__ float dot256_f32(const float* __restrict__ x,
                                            const float* __restrict__ w) {
    const float4* __restrict__ xv = (const float4*)x;
    const float4* __restrict__ wv = (const float4*)w;
    float a0 = 0.f, a1 = 0.f, a2 = 0.f, a3 = 0.f;
#pragma unroll 8
    for (int k = 0; k < 64; ++k) {
        float4 xu = xv[k], wu = wv[k];
        a0 = fmaf(xu.x, wu.x, a0);
        a1 = fmaf(xu.y, wu.y, a1);
        a2 = fmaf(xu.z, wu.z, a2);
        a3 = fmaf(xu.w, wu.w, a3);
    }
    return (a0 + a1) + (a2 + a3);
}

__device__ __forceinline__ float do_dot(const void* X, const void* W,
                                        long xb, int wrow, bool f32) {
    return f32 ? dot256_f32((const float*)X + xb, (const float*)W + wrow)
               : dot256_bf16((const unsigned short*)X + xb,
                             (const unsigned short*)W + wrow);
}

__global__ __launch_bounds__(1024) void qlstm_fused(
    const void* __restrict__ X,  const void* __restrict__ hx, const void* __restrict__ cx,
    const void* __restrict__ Wf, const void* __restrict__ bf_,
    const void* __restrict__ Wi, const void* __restrict__ bi_,
    const void* __restrict__ Wu, const void* __restrict__ bu_,
    const void* __restrict__ Wo, const void* __restrict__ bo_,
    const void* __restrict__ tf, const void* __restrict__ ti,
    const void* __restrict__ tu, const void* __restrict__ to_,
    void* __restrict__ out)
{
    __shared__ float As[S_LEN][32];   // 32 KiB: A[t][o]
    __shared__ int s_isf32;

    const int tid = threadIdx.x;
    const int b   = blockIdx.x;

    // ---- dtype sniff: bf16 storage -> even-index ushorts are bf16 of N(0,1)
    // (exponent near 127); fp32 -> low mantissa bits, exponent-field uniform.
    if (tid == 0) {
        const unsigned short* u = (const unsigned short*)X;
        int hits = 0;
        for (int i = 0; i < 64; ++i) {
            int e = (u[2 * i] >> 7) & 0xFF;
            if (e >= 110 && e <= 135) ++hits;
        }
        s_isf32 = (hits < 32) ? 1 : 0;
    }
    __syncthreads();
    const bool f32 = (s_isf32 != 0);

    // ---- prologue: chunk 0 filled by all 1024 threads (1 dot each)
    {
        const int o = tid & 31, g = o >> 3, w = o & 7;
        const void* W = (g == 0) ? Wf : (g == 1) ? Wi : (g == 2) ? Wu : Wo;
        const int tl = tid >> 5;                       // 0..31
        const long xb = ((long)tl * BATCH + b) * DIMK;
        As[tl][o] = sane(do_dot(X, W, xb, w * FAN, f32));
    }

    // ---- recurrence state (lanes 0..31 of wave 0)
    float Wh[8];
    float bt = 0.f, h = 0.f, c = 0.f, qv = 1.f;
    int rw = 0, rg = 0;
    if (tid < 32) {
        rw = tid & 7; rg = tid >> 3;
        const void* W  = (rg == 0) ? Wf  : (rg == 1) ? Wi  : (rg == 2) ? Wu  : Wo;
        const void* bg = (rg == 0) ? bf_ : (rg == 1) ? bi_ : (rg == 2) ? bu_ : bo_;
        const void* tg = (rg == 0) ? tf  : (rg == 1) ? ti  : (rg == 2) ? tu  : to_;
        const int wr = rw * FAN;
#pragma unroll
        for (int j = 0; j < 8; ++j)
            Wh[j] = sane(ldE(W, wr + DIMK + j, f32));
        bt = sane(ldE(bg, rw, f32)) + sane(ldE(tg, rw, f32));
        h  = sane(ldE(hx, b * 8 + rw, f32));
        c  = sane(ldE(cx, b * 8 + rw, f32));
        qv = (rg == 2) ? 2.f : 1.f;   // 1 -> sigmoid, 2 -> tanh (unified form)
    }
    __syncthreads();   // chunk 0 + state ready (uniform barrier)

    // ---- pipelined main loop: waves 1-15 fill chunk ch+1, wave 0 runs ch
    for (int ch = 0; ch < NCH; ++ch) {
        if (tid >= 64 && ch + 1 < NCH) {
            const int q = tid - 64;                    // 0..959
            for (int idx = q; idx < CHUNK * 32; idx += 960) {  // wave-uniform trip
                const int o = idx & 31, g = o >> 3, w = o & 7;
                const int tl = (ch + 1) * CHUNK + (idx >> 5);
                const void* W = (g == 0) ? Wf : (g == 1) ? Wi : (g == 2) ? Wu : Wo;
                const long xb = ((long)tl * BATCH + b) * DIMK;
                As[tl][o] = sane(do_dot(X, W, xb, w * FAN, f32));
            }
        }
        if (tid < 32) {
            for (int s = 0; s < CHUNK; ++s) {
                const int t = ch * CHUNK + s;
                float a = As[t][tid];

                // h-dot via v_readlane (h replicated across gate groups)
                float d0 = 0.f, d1 = 0.f;
#pragma unroll
                for (int j = 0; j < 8; j += 2) {
                    d0 = fmaf(rdlane_f(h, j),     Wh[j],     d0);
                    d1 = fmaf(rdlane_f(h, j + 1), Wh[j + 1], d1);
                }
                float ang = a + bt + (d0 + d1);
                float e = __cosf(ang);

                // inclusive cumprod over 8-lane group via DPP row_shr
                { float v = dpp_f<0x111>(e); e = (rw >= 1) ? e * v : e; }
                { float v = dpp_f<0x112>(e); e = (rw >= 2) ? e * v : e; }
                { float v = dpp_f<0x114>(e); e = (rw >= 4) ? e * v : e; }

                // own-gate nonlinearity: 1 - q/(exp(q*E)+1); q=1 sigm, q=2 tanh
                float ez  = __expf(qv * e);
                float val = 1.f - __fdividef(qv, ez + 1.f);

                // gather the 4 transformed gates for this wire (one LDS round)
                float fg = swz_f<0x007>(val);          // lane  w
                float ig = swz_f<0x107>(val);          // lane  8+w
                float ug = swz_f<0x207>(val);          // lane 16+w
                float og = swz_f<0x307>(val);          // lane 24+w

                c = fmaf(fg, c, ig * ug);
                float e2 = __expf(2.f * c);
                float th = 1.f - __fdividef(2.f, e2 + 1.f);
                h = og * th;

                if (rg == 0)
                    stE(out, (long)t * 2048 + b * 8 + rw, h, f32);
            }
        }
        __syncthreads();   // uniform: every thread reaches it each chunk
    }

    if (tid < 32 && rg == 0) {
        stE(out, 524288L + b * 8 + rw, h, f32);   // hT
        stE(out, 526336L + b * 8 + rw, c, f32);   // cT
    }
}

extern "C" void kernel_launch(void* const* d_in, const int* in_sizes, int n_in,
                              void* d_out, int out_size, void* d_ws, size_t ws_size,
                              hipStream_t stream) {
    qlstm_fused<<<dim3(BATCH), dim3(1024), 0, stream>>>(
        d_in[0], d_in[1], d_in[2],
        d_in[3], d_in[4], d_in[5], d_in[6],
        d_in[7], d_in[8], d_in[9], d_in[10],
        d_in[11], d_in[12], d_in[13], d_in[14],
        d_out);
}